// Round 1
// baseline (506.302 us; speedup 1.0000x reference)
//
#include <hip/hip_runtime.h>
#include <hip/hip_bf16.h>
#include <stdint.h>

#define HID 256
#define BM  64
#define BK  64
#define LDT 72   // padded LDS row stride in bf16 elems (144 B: 16B-aligned, 2-way bank alias only)

typedef __bf16 bf16x8 __attribute__((ext_vector_type(8)));
typedef float  f32x4  __attribute__((ext_vector_type(4)));

__device__ __forceinline__ ushort f2bf(float x) {
    union { float f; uint32_t u; } v; v.f = x;
    uint32_t u = v.u;
    uint32_t r = u + 0x7fffu + ((u >> 16) & 1u);   // round-to-nearest-even
    return (ushort)(r >> 16);
}

// Transpose+convert W1[512][256] fp32 -> Wt[256][512] bf16 (workspace)
__global__ void conv_w1(const float* __restrict__ W1, ushort* __restrict__ Wt) {
    int t = blockIdx.x * 256 + threadIdx.x;   // 0..131071
    int n = t >> 9;                            // col of W1 (0..255)
    int k = t & 511;                           // row of W1 (0..511)
    Wt[t] = f2bf(W1[(size_t)k * HID + n]);
}

__global__ __launch_bounds__(256, 2)
void lp_gemm(const float* __restrict__ emb_src, const float* __restrict__ emb_dst,
             const int* __restrict__ eli,
             const ushort* __restrict__ Wt,     // bf16 [256][512], transposed W1 (may be unused)
             const float* __restrict__ W1,      // fallback if ws too small
             const float* __restrict__ b1, const float* __restrict__ W2,
             const float* __restrict__ b2,
             float* __restrict__ out, int E, int useWt) {
    __shared__ __align__(16) ushort As[BM * LDT];     // 9216 B
    __shared__ __align__(16) ushort Bs[HID * LDT];    // 36864 B
    __shared__ int   sIdx[2][BM];                     // 512 B
    __shared__ float hred[4][BM];                     // 1024 B

    const int t    = threadIdx.x;
    const int blk  = blockIdx.x;
    const int e0   = blk * BM;
    const int wave = t >> 6;
    const int lane = t & 63;
    const int q    = lane >> 4;
    const int cl   = lane & 15;

    // load edge indices (clamped for the tail block)
    if (t < 2 * BM) {
        int which = t >> 6;           // 0 = src row, 1 = dst row
        int e     = t & (BM - 1);
        int ge    = e0 + e; if (ge > E - 1) ge = E - 1;
        sIdx[which][e] = eli[which * E + ge];
    }
    __syncthreads();

    f32x4 acc[4][4] = {};

    for (int c = 0; c < 8; ++c) {
        // ---- stage A: gather 64 rows x 64 fp32, convert to bf16 ----
        const float* tab  = (c < 4) ? emb_src : emb_dst;
        const int*   idxs = sIdx[c >> 2];
        const int    kcol = (c & 3) * 64;
        #pragma unroll
        for (int i = 0; i < 4; ++i) {
            int c2  = t + 256 * i;     // 0..1023
            int e   = c2 >> 4;         // row 0..63
            int off = c2 & 15;         // float4 offset 0..15
            const float4 v = *reinterpret_cast<const float4*>(
                &tab[(size_t)idxs[e] * HID + kcol + off * 4]);
            ushort4 bv;
            bv.x = f2bf(v.x); bv.y = f2bf(v.y); bv.z = f2bf(v.z); bv.w = f2bf(v.w);
            *reinterpret_cast<ushort4*>(&As[e * LDT + off * 4]) = bv;
        }
        // ---- stage B: 256 rows x 64 bf16 of Wt (k-chunk c) ----
        if (useWt) {
            #pragma unroll
            for (int i = 0; i < 8; ++i) {
                int c2  = t + 256 * i;   // 0..2047
                int n   = c2 >> 3;       // 0..255
                int off = c2 & 7;        // 16B chunk 0..7
                uint4 wv = *reinterpret_cast<const uint4*>(
                    &Wt[(size_t)n * 512 + c * 64 + off * 8]);
                *reinterpret_cast<uint4*>(&Bs[n * LDT + off * 8]) = wv;
            }
        } else {
            // fallback: transpose-convert from W1 fp32 on the fly (slow but correct)
            #pragma unroll
            for (int i = 0; i < 8; ++i) {
                int c2  = t + 256 * i;
                int n   = c2 >> 3;
                int off = c2 & 7;
                union { ushort s[8]; uint4 v; } u;
                #pragma unroll
                for (int j = 0; j < 8; ++j)
                    u.s[j] = f2bf(W1[(size_t)(c * 64 + off * 8 + j) * HID + n]);
                *reinterpret_cast<uint4*>(&Bs[n * LDT + off * 8]) = u.v;
            }
        }
        __syncthreads();

        // ---- compute: 32 MFMAs per wave per chunk ----
        #pragma unroll
        for (int ks = 0; ks < 2; ++ks) {
            bf16x8 af[4], bfr[4];
            #pragma unroll
            for (int mi = 0; mi < 4; ++mi)
                af[mi] = *reinterpret_cast<const bf16x8*>(
                    &As[(mi * 16 + cl) * LDT + ks * 32 + q * 8]);
            #pragma unroll
            for (int ni = 0; ni < 4; ++ni)
                bfr[ni] = *reinterpret_cast<const bf16x8*>(
                    &Bs[(wave * 64 + ni * 16 + cl) * LDT + ks * 32 + q * 8]);
            #pragma unroll
            for (int mi = 0; mi < 4; ++mi)
                #pragma unroll
                for (int ni = 0; ni < 4; ++ni)
                    acc[mi][ni] = __builtin_amdgcn_mfma_f32_16x16x32_bf16(
                        af[mi], bfr[ni], acc[mi][ni], 0, 0, 0);
        }
        __syncthreads();
    }

    // ---- epilogue: h = relu(acc + b1); partial = h . W2 (fused, fp32) ----
    float b1v[4], w2v[4];
    #pragma unroll
    for (int ni = 0; ni < 4; ++ni) {
        int col = wave * 64 + ni * 16 + cl;
        b1v[ni] = b1[col];
        w2v[ni] = W2[col];
    }
    #pragma unroll
    for (int mi = 0; mi < 4; ++mi) {
        #pragma unroll
        for (int r = 0; r < 4; ++r) {
            float s = 0.f;
            #pragma unroll
            for (int ni = 0; ni < 4; ++ni) {
                float h = acc[mi][ni][r] + b1v[ni];
                h = fmaxf(h, 0.f);
                s += h * w2v[ni];
            }
            // reduce over the 16 lanes of this quad (cols)
            s += __shfl_xor(s, 1);
            s += __shfl_xor(s, 2);
            s += __shfl_xor(s, 4);
            s += __shfl_xor(s, 8);
            if (cl == 0) hred[wave][mi * 16 + q * 4 + r] = s;
        }
    }
    __syncthreads();
    if (t < BM) {
        int ge = e0 + t;
        if (ge < E)
            out[ge] = hred[0][t] + hred[1][t] + hred[2][t] + hred[3][t] + b2[0];
    }
}

extern "C" void kernel_launch(void* const* d_in, const int* in_sizes, int n_in,
                              void* d_out, int out_size, void* d_ws, size_t ws_size,
                              hipStream_t stream) {
    const float* emb_src = (const float*)d_in[0];
    const float* emb_dst = (const float*)d_in[1];
    const int*   eli     = (const int*)d_in[2];
    const float* W1      = (const float*)d_in[3];
    const float* b1      = (const float*)d_in[4];
    const float* W2      = (const float*)d_in[5];
    const float* b2      = (const float*)d_in[6];
    float*       out     = (float*)d_out;

    const int E = in_sizes[2] / 2;
    const size_t wt_bytes = (size_t)HID * 2 * HID * sizeof(ushort);  // 256 KB
    const int useWt = (ws_size >= wt_bytes) ? 1 : 0;
    ushort* Wt = (ushort*)d_ws;

    if (useWt)
        conv_w1<<<512, 256, 0, stream>>>(W1, Wt);

    const int nb = (E + BM - 1) / BM;
    lp_gemm<<<nb, 256, 0, stream>>>(emb_src, emb_dst, eli, Wt, W1, b1, W2, b2,
                                    out, E, useWt);
}